// Round 4
// baseline (568.090 us; speedup 1.0000x reference)
//
#include <hip/hip_runtime.h>

// Problem constants (match reference setup_inputs()).
#define HW_DIM 1024
#define LATD   32
#define HIDD   64

// Packed-fp32: <4 x float> fma lowers to v_pk_fma_f32 on gfx90a+/gfx950.
typedef float v4f __attribute__((ext_vector_type(4)));

// ---------------------------------------------------------------------------
// Pre-kernel: transpose W1 (64x32 -> 32x64) and W2 (64x64 -> 64x64) into d_ws
// so the main kernel can accumulate outer-product style with contiguous
// (wave-uniform, s_load-able) weight rows. 6144 elements total -> ~2 us.
// Runs every call (graph-capture safe, no state).
// ---------------------------------------------------------------------------
__global__ __launch_bounds__(256) void transpose_weights_kernel(
    const float* __restrict__ W1,   // 64x32 row-major
    const float* __restrict__ W2,   // 64x64 row-major
    float*       __restrict__ w1t,  // 32x64
    float*       __restrict__ w2t)  // 64x64
{
    const int t = blockIdx.x * blockDim.x + threadIdx.x;
    if (t < 64 * 32) {
        const int j = t >> 5;                 // W1 row (output neuron)
        const int l = t & 31;                 // W1 col (input)
        w1t[l * 64 + j] = W1[t];
    } else if (t < 64 * 32 + 64 * 64) {
        const int t2 = t - 64 * 32;
        const int j = t2 >> 6;
        const int l = t2 & 63;
        w2t[l * 64 + j] = W2[t2];
    }
}

// ---------------------------------------------------------------------------
// Main kernel: one thread per query. Accumulator-form MLP:
//   - output vector of each layer lives in v4f VGPRs,
//   - acc[c] += act[l] * Wt[l][c]  -> pure packed FMA, zero horizontal
//     reductions (bias = init, ReLU = elementwise),
//   - all activation element extractions are compile-time (full unroll),
//   - weight addresses wave-uniform -> scalar path.
// Layer 2 chunked into 2x32 outputs: peak live VGPR ~ 64(h1)+32(acc)+misc.
// ---------------------------------------------------------------------------
__global__ __launch_bounds__(256) void fused_model_kernel(
    const int2*   __restrict__ queries,       // B x (row,col)
    const int4*   __restrict__ neighbor_map,  // H*W entries of K=4 ids
    const float2* __restrict__ positions,     // N x 2
    const v4f*    __restrict__ embeddings,    // N x 8 v4f (32 floats/row)
    const v4f*    __restrict__ w1t,           // 32 rows x 16 v4f (transposed W1)
    const float*  __restrict__ b1,            // 64
    const v4f*    __restrict__ w2t,           // 64 rows x 16 v4f (transposed W2)
    const float*  __restrict__ b2,            // 64
    const float*  __restrict__ W3,            // 3x64 row-major
    const float*  __restrict__ b3,            // 3
    const float*  __restrict__ mu,            // 3
    const float*  __restrict__ sd,            // 3
    float*        __restrict__ out,           // B x 3
    int B)
{
#pragma clang fp contract(fast)
    const int tid = blockIdx.x * blockDim.x + threadIdx.x;
    if (tid >= B) return;

    // ---- gather neighbors ----
    const int2 q  = queries[tid];
    const int4 nb = neighbor_map[q.x * HW_DIM + q.y];
    const float qx = (float)q.x;
    const float qy = (float)q.y;

    const float2 p0 = positions[nb.x];
    const float2 p1 = positions[nb.y];
    const float2 p2 = positions[nb.z];
    const float2 p3 = positions[nb.w];

    const float d0 = sqrtf((p0.x - qx) * (p0.x - qx) + (p0.y - qy) * (p0.y - qy));
    const float d1 = sqrtf((p1.x - qx) * (p1.x - qx) + (p1.y - qy) * (p1.y - qy));
    const float d2 = sqrtf((p2.x - qx) * (p2.x - qx) + (p2.y - qy) * (p2.y - qy));
    const float d3 = sqrtf((p3.x - qx) * (p3.x - qx) + (p3.y - qy) * (p3.y - qy));

    // ---- latent = sum_k d_k * emb[n_k]  (8 x v4f in registers) ----
    const v4f* e0 = embeddings + nb.x * 8;
    const v4f* e1 = embeddings + nb.y * 8;
    const v4f* e2 = embeddings + nb.z * 8;
    const v4f* e3 = embeddings + nb.w * 8;

    v4f lat[8];
#pragma unroll
    for (int c = 0; c < 8; ++c)
        lat[c] = (e0[c] * d0 + e1[c] * d1) + (e2[c] * d2 + e3[c] * d3);

    // ---- layer 1 (accumulator form): h1 = relu(b1 + sum_l lat[l]*w1t[l][:]) ----
    v4f h1[16];
    const v4f* b1v = (const v4f*)b1;
#pragma unroll
    for (int c = 0; c < 16; ++c) h1[c] = b1v[c];

#pragma unroll
    for (int l = 0; l < LATD; ++l) {
        const float s  = lat[l >> 2][l & 3];    // compile-time element idx
        const v4f* wr = w1t + l * 16;
#pragma unroll
        for (int c = 0; c < 16; ++c)
            h1[c] += s * wr[c];                 // v_pk_fma_f32 (splat s)
    }
#pragma unroll
    for (int c = 0; c < 16; ++c) {
        h1[c].x = fmaxf(h1[c].x, 0.0f);
        h1[c].y = fmaxf(h1[c].y, 0.0f);
        h1[c].z = fmaxf(h1[c].z, 0.0f);
        h1[c].w = fmaxf(h1[c].w, 0.0f);
    }

    // ---- layers 2+3, output-chunked (2 x 32 neurons) to cap VGPR ----
    float o0 = b3[0], o1 = b3[1], o2 = b3[2];
#pragma unroll
    for (int ch = 0; ch < 2; ++ch) {
        v4f acc[8];
        const v4f* b2v = (const v4f*)b2 + ch * 8;
#pragma unroll
        for (int u = 0; u < 8; ++u) acc[u] = b2v[u];

#pragma unroll
        for (int l = 0; l < HIDD; ++l) {
            const float s  = h1[l >> 2][l & 3]; // compile-time element idx
            const v4f* wr = w2t + l * 16 + ch * 8;
#pragma unroll
            for (int u = 0; u < 8; ++u)
                acc[u] += s * wr[u];            // v_pk_fma_f32
        }

        // ReLU + layer-3 partial (W3 rows contiguous, wave-uniform)
        const v4f* w3r0 = (const v4f*)(W3 + 0 * HIDD) + ch * 8;
        const v4f* w3r1 = (const v4f*)(W3 + 1 * HIDD) + ch * 8;
        const v4f* w3r2 = (const v4f*)(W3 + 2 * HIDD) + ch * 8;
        v4f a0 = {0, 0, 0, 0}, a1 = {0, 0, 0, 0}, a2 = {0, 0, 0, 0};
#pragma unroll
        for (int u = 0; u < 8; ++u) {
            v4f t = acc[u];
            t.x = fmaxf(t.x, 0.0f);
            t.y = fmaxf(t.y, 0.0f);
            t.z = fmaxf(t.z, 0.0f);
            t.w = fmaxf(t.w, 0.0f);
            a0 += w3r0[u] * t;
            a1 += w3r1[u] * t;
            a2 += w3r2[u] * t;
        }
        o0 += (a0.x + a0.y) + (a0.z + a0.w);
        o1 += (a1.x + a1.y) + (a1.z + a1.w);
        o2 += (a2.x + a2.y) + (a2.z + a2.w);
    }

    // ---- affine + clip + store ----
    const float r0 = fminf(fmaxf(fmaf(o0, sd[0], mu[0]), 0.0f), 1.0f);
    const float r1 = fminf(fmaxf(fmaf(o1, sd[1], mu[1]), 0.0f), 1.0f);
    const float r2 = fminf(fmaxf(fmaf(o2, sd[2], mu[2]), 0.0f), 1.0f);
    out[tid * 3 + 0] = r0;
    out[tid * 3 + 1] = r1;
    out[tid * 3 + 2] = r2;
}

extern "C" void kernel_launch(void* const* d_in, const int* in_sizes, int n_in,
                              void* d_out, int out_size, void* d_ws, size_t ws_size,
                              hipStream_t stream) {
    const int2*   queries      = (const int2*)d_in[0];
    const int4*   neighbor_map = (const int4*)d_in[1];
    const float2* positions    = (const float2*)d_in[2];
    const v4f*    embeddings   = (const v4f*)d_in[3];
    const float*  W1 = (const float*)d_in[4];
    const float*  b1 = (const float*)d_in[5];
    const float*  W2 = (const float*)d_in[6];
    const float*  b2 = (const float*)d_in[7];
    const float*  W3 = (const float*)d_in[8];
    const float*  b3 = (const float*)d_in[9];
    const float*  mu = (const float*)d_in[10];
    const float*  sd = (const float*)d_in[11];
    float* out = (float*)d_out;

    // Scratch layout: w1t = 32x64 floats, w2t = 64x64 floats (24.5 KB total).
    float* w1t = (float*)d_ws;
    float* w2t = w1t + 64 * 32;

    transpose_weights_kernel<<<(64 * 32 + 64 * 64 + 255) / 256, 256, 0, stream>>>(
        W1, W2, w1t, w2t);

    const int B = in_sizes[0] / 2;  // queries is B x 2
    const int threads = 256;
    const int blocks = (B + threads - 1) / threads;

    fused_model_kernel<<<blocks, threads, 0, stream>>>(
        queries, neighbor_map, positions, embeddings,
        (const v4f*)w1t, b1, (const v4f*)w2t, b2, W3, b3, mu, sd, out, B);
}